// Round 7
// baseline (865.372 us; speedup 1.0000x reference)
//
#include <hip/hip_runtime.h>
#include <cstdint>

typedef unsigned short u16;
typedef unsigned int u32;
typedef __attribute__((ext_vector_type(8))) short short8;   // 8 bf16 (MFMA A/B frag)
typedef __attribute__((ext_vector_type(4))) float floatx4;  // MFMA C/D frag
typedef __attribute__((ext_vector_type(2))) float floatx2;  // packed f32 pair (v_pk_*_f32)

__device__ __forceinline__ float b2f(u16 u) {
    union { unsigned int i; float f; } c; c.i = ((unsigned int)u) << 16; return c.f;
}
__device__ __forceinline__ u16 f2b(float f) {
    union { float f; unsigned int i; } c; c.f = f;
    unsigned int u = c.i;
    u = u + 0x7FFFu + ((u >> 16) & 1u);   // RNE
    return (u16)(u >> 16);
}
__device__ __forceinline__ float u2f(u32 u) { union { u32 u; float f; } c; c.u = u; return c.f; }

// ---------------------------------------------------------------------------
// Fused Q/K/V projection GEMM. Y[m,n] = sum_k x[m,k]*W[n,k] + bias[n].
// grid (32, 24): which = blockIdx.y>>3 (0=q fp32, 1=k bf16, 2=v).
// For which==2 the 64x64 tile is transposed through LDS and stored CHUNK-MAJOR
// as vt[bh][chunk=c>>5][dt=d>>4][d&15][c&31] (bf16 hi + bf16 lo residual) so
// the attention PV step loads B-frags via one walking pointer + imm offsets.
// ---------------------------------------------------------------------------
__global__ __launch_bounds__(256) void gemm_qkv(
    const float* __restrict__ x,
    const float* __restrict__ Wq, const float* __restrict__ Wk, const float* __restrict__ Wv,
    const float* __restrict__ bq, const float* __restrict__ bk, const float* __restrict__ bv,
    float* __restrict__ qout, u16* __restrict__ kout,
    u16* __restrict__ vthi, u16* __restrict__ vtlo)
{
    __shared__ u16 xs[64 * 72];
    __shared__ u16 wsl[64 * 72];
    int tid = threadIdx.x;
    int lane = tid & 63;
    int wv = tid >> 6;
    int lo = lane & 15, hi = lane >> 4;
    int which = blockIdx.y >> 3;
    int m0 = blockIdx.x * 64, n0 = (blockIdx.y & 7) * 64;
    const float* W    = which == 0 ? Wq : (which == 1 ? Wk : Wv);
    const float* bias = which == 0 ? bq : (which == 1 ? bk : bv);

    floatx4 acc[4];
#pragma unroll
    for (int mt = 0; mt < 4; ++mt) acc[mt] = (floatx4){0.f, 0.f, 0.f, 0.f};

    for (int k0 = 0; k0 < 512; k0 += 64) {
        __syncthreads();
#pragma unroll
        for (int i = 0; i < 2; ++i) {
            int v = tid + i * 256;
            int row = v >> 3, c8 = (v & 7) * 8;
            const float* ap = x + (m0 + row) * 512 + k0 + c8;
            const float* wp = W + (n0 + row) * 512 + k0 + c8;
            float4 a0 = *(const float4*)(ap);
            float4 a1 = *(const float4*)(ap + 4);
            float4 w0 = *(const float4*)(wp);
            float4 w1v = *(const float4*)(wp + 4);
            union { u16 u[8]; uint4 q; } ca, cw;
            ca.u[0] = f2b(a0.x); ca.u[1] = f2b(a0.y); ca.u[2] = f2b(a0.z); ca.u[3] = f2b(a0.w);
            ca.u[4] = f2b(a1.x); ca.u[5] = f2b(a1.y); ca.u[6] = f2b(a1.z); ca.u[7] = f2b(a1.w);
            cw.u[0] = f2b(w0.x); cw.u[1] = f2b(w0.y); cw.u[2] = f2b(w0.z); cw.u[3] = f2b(w0.w);
            cw.u[4] = f2b(w1v.x); cw.u[5] = f2b(w1v.y); cw.u[6] = f2b(w1v.z); cw.u[7] = f2b(w1v.w);
            *(uint4*)(xs + row * 72 + c8)  = ca.q;
            *(uint4*)(wsl + row * 72 + c8) = cw.q;
        }
        __syncthreads();
#pragma unroll
        for (int ks = 0; ks < 2; ++ks) {
            short8 bfr = *(const short8*)(wsl + (wv * 16 + lo) * 72 + ks * 32 + hi * 8);
#pragma unroll
            for (int mt = 0; mt < 4; ++mt) {
                short8 afr = *(const short8*)(xs + (mt * 16 + lo) * 72 + ks * 32 + hi * 8);
                acc[mt] = __builtin_amdgcn_mfma_f32_16x16x32_bf16(afr, bfr, acc[mt], 0, 0, 0);
            }
        }
    }

    int n = n0 + wv * 16 + lo;
    float bv2 = bias[n];
    if (which == 2) {
        // transpose V tile through LDS; emit vt_hi/vt_lo bf16, chunk-major layout
        __syncthreads();                           // xs/wsl reuse: all waves done with MFMAs
        int nl = wv * 16 + lo;                     // local d
#pragma unroll
        for (int mt = 0; mt < 4; ++mt)
#pragma unroll
            for (int r = 0; r < 4; ++r) {
                int ml = mt * 16 + hi * 4 + r;     // local c
                float y = acc[mt][r] + bv2;
                u16 vh = f2b(y);
                u16 vl = f2b(y - b2f(vh));
                xs[nl * 72 + ml]  = vh;
                wsl[nl * 72 + ml] = vl;
            }
        __syncthreads();
        int row = tid >> 2, seg = (tid & 3) * 16;  // row = local d, seg = local c chunk
        int b = m0 >> 10, c0 = m0 & 1023, h2 = n0 >> 6;
        int cc = c0 + seg;                         // global c of this 16-piece (within one 32-chunk)
        size_t dst = (size_t)(b * 8 + h2) * 65536 + (cc >> 5) * 2048
                   + (row >> 4) * 512 + (row & 15) * 32 + (cc & 31);
        *(uint4*)(vthi + dst)     = *(uint4*)(xs  + row * 72 + seg);
        *(uint4*)(vthi + dst + 8) = *(uint4*)(xs  + row * 72 + seg + 8);
        *(uint4*)(vtlo + dst)     = *(uint4*)(wsl + row * 72 + seg);
        *(uint4*)(vtlo + dst + 8) = *(uint4*)(wsl + row * 72 + seg + 8);
    } else {
        int h = n >> 6, dd = n & 63;
#pragma unroll
        for (int mt = 0; mt < 4; ++mt)
#pragma unroll
            for (int r = 0; r < 4; ++r) {
                int m = m0 + mt * 16 + hi * 4 + r;  // C/D: row=(lane>>4)*4+reg, col=lane&15
                float y = acc[mt][r] + bv2;
                int b = m >> 10, c = m & 1023;
                int idx = (((b * 8 + h) * 1024) + c) * 64 + dd;
                if (which == 0) qout[idx] = y;
                else            kout[idx] = f2b(y);
            }
    }
}

// ---------------------------------------------------------------------------
// Output GEMM: Y[m,n] = sum_k A[m,k]*Wo[n,k] + bo[n], fp32 out, [m*512+n].
// ---------------------------------------------------------------------------
__global__ __launch_bounds__(256) void gemm_out(
    const float* __restrict__ A, const float* __restrict__ W, const float* __restrict__ bias,
    float* __restrict__ outf)
{
    __shared__ u16 xs[64 * 72];
    __shared__ u16 wsl[64 * 72];
    int tid = threadIdx.x;
    int lane = tid & 63;
    int wv = tid >> 6;
    int lo = lane & 15, hi = lane >> 4;
    int m0 = blockIdx.x * 64, n0 = blockIdx.y * 64;

    floatx4 acc[4];
#pragma unroll
    for (int mt = 0; mt < 4; ++mt) acc[mt] = (floatx4){0.f, 0.f, 0.f, 0.f};

    for (int k0 = 0; k0 < 512; k0 += 64) {
        __syncthreads();
#pragma unroll
        for (int i = 0; i < 2; ++i) {
            int v = tid + i * 256;
            int row = v >> 3, c8 = (v & 7) * 8;
            const float* ap = A + (m0 + row) * 512 + k0 + c8;
            const float* wp = W + (n0 + row) * 512 + k0 + c8;
            float4 a0 = *(const float4*)(ap);
            float4 a1 = *(const float4*)(ap + 4);
            float4 w0 = *(const float4*)(wp);
            float4 w1v = *(const float4*)(wp + 4);
            union { u16 u[8]; uint4 q; } ca, cw;
            ca.u[0] = f2b(a0.x); ca.u[1] = f2b(a0.y); ca.u[2] = f2b(a0.z); ca.u[3] = f2b(a0.w);
            ca.u[4] = f2b(a1.x); ca.u[5] = f2b(a1.y); ca.u[6] = f2b(a1.z); ca.u[7] = f2b(a1.w);
            cw.u[0] = f2b(w0.x); cw.u[1] = f2b(w0.y); cw.u[2] = f2b(w0.z); cw.u[3] = f2b(w0.w);
            cw.u[4] = f2b(w1v.x); cw.u[5] = f2b(w1v.y); cw.u[6] = f2b(w1v.z); cw.u[7] = f2b(w1v.w);
            *(uint4*)(xs + row * 72 + c8)  = ca.q;
            *(uint4*)(wsl + row * 72 + c8) = cw.q;
        }
        __syncthreads();
#pragma unroll
        for (int ks = 0; ks < 2; ++ks) {
            short8 bfr = *(const short8*)(wsl + (wv * 16 + lo) * 72 + ks * 32 + hi * 8);
#pragma unroll
            for (int mt = 0; mt < 4; ++mt) {
                short8 afr = *(const short8*)(xs + (mt * 16 + lo) * 72 + ks * 32 + hi * 8);
                acc[mt] = __builtin_amdgcn_mfma_f32_16x16x32_bf16(afr, bfr, acc[mt], 0, 0, 0);
            }
        }
    }

    int n = n0 + wv * 16 + lo;
    float bv = bias[n];
#pragma unroll
    for (int mt = 0; mt < 4; ++mt)
#pragma unroll
        for (int r = 0; r < 4; ++r) {
            int m = m0 + mt * 16 + hi * 4 + r;
            outf[m * 512 + n] = acc[mt][r] + bv;
        }
}

// ---------------------------------------------------------------------------
// Fused second-order attention, v19: INDEPENDENT WAVES (v18 post-mortem:
// latency-bound, 41% idle, barrier-locked waves stall in phase; VALU diet
// gave -17% issue but -2% time). Each wave now computes its own query's FULL
// d=64 output, so P never crosses waves:
//  - P staged in a 64-byte wave-private LDS plane (2 ds_write_b16 lanes<16,
//    1 broadcast ds_read_b128); every A-frag row holds the same P row so all
//    D rows equal the true output (read row 0).
//  - PV = 8 MFMAs/chunk (4 d-tiles x V hi/lo) from chunk-major V^T.
//  - ZERO __syncthreads in the kernel; waves drift and stalls decorrelate.
//  - rank-1 qp' moved from AGPR C-init (16 regs + 4 MFMAs) into scoring as a
//    packed bf16 add (qpp, +1 pk_add/pair) to pay for pvacc 4->16 AGPRs.
//  - vh loads issued at chunk top (full-chunk latency), vl after scoring.
// ---------------------------------------------------------------------------
__global__ __launch_bounds__(256, 4) void attn19(
    const float* __restrict__ qf, const u16* __restrict__ kb,
    const u16* __restrict__ vthi, const u16* __restrict__ vtlo,
    const float* __restrict__ w1, const float* __restrict__ b1, const float* __restrict__ w2,
    float* __restrict__ ao)
{
    __shared__ float q_l[4 * 64];
    __shared__ __align__(16) u16 p_sw[4 * 32];     // per-wave P staging (64 B each)
    int tid = threadIdx.x;
    int lane = tid & 63;
    int wv = tid >> 6;
    int lo = lane & 15, hi = lane >> 4;
    int bh = blockIdx.x >> 8;                      // 0..15 = b*8+h
    int qbase = (blockIdx.x & 255) << 2;           // block's first query
    int qi = qbase | wv;                           // this wave's query

    const float NA = -2.45546696f;                 // -1.702 * log2(e)

    q_l[wv * 64 + lane] = qf[(bh * 1024 + qi) * 64 + lane];   // wave-private segment

    // qp[e]+b1[e] at lane=e
    float qpacc = b1[lane];
#pragma unroll
    for (int d8 = 0; d8 < 64; d8 += 8) {
        float4 wa = *(const float4*)(w1 + lane * 192 + d8);
        float4 wb = *(const float4*)(w1 + lane * 192 + d8 + 4);
        const float* q8 = q_l + wv * 64 + d8;      // wave-uniform broadcast reads
        qpacc = __builtin_fmaf(q8[0], wa.x, qpacc);
        qpacc = __builtin_fmaf(q8[1], wa.y, qpacc);
        qpacc = __builtin_fmaf(q8[2], wa.z, qpacc);
        qpacc = __builtin_fmaf(q8[3], wa.w, qpacc);
        qpacc = __builtin_fmaf(q8[4], wb.x, qpacc);
        qpacc = __builtin_fmaf(q8[5], wb.y, qpacc);
        qpacc = __builtin_fmaf(q8[6], wb.z, qpacc);
        qpacc = __builtin_fmaf(q8[7], wb.w, qpacc);
    }
    qpacc *= NA;                                   // qp' = c * (qp + b1)

    // w2c packed: wc' = w2[e] * (1/8)*log2e / c ; qp' packed the same way
    u32 wcp[4][2];
    u32 qpp[4][2];
    float w2row = w2[lane] * -0.07344288f;
#pragma unroll
    for (int mt = 0; mt < 4; ++mt)
#pragma unroll
        for (int h2 = 0; h2 < 2; ++h2) {
            int e0 = mt * 16 + hi * 4 + h2 * 2;
            u32 wlo = (u32)f2b(__shfl(w2row, e0));
            u32 whi = (u32)f2b(__shfl(w2row, e0 + 1));
            wcp[mt][h2] = (whi << 16) | wlo;
            u32 qlo = (u32)f2b(__shfl(qpacc, e0));
            u32 qhi = (u32)f2b(__shfl(qpacc, e0 + 1));
            qpp[mt][h2] = (qhi << 16) | qlo;
        }

    // q pieces for frag build: qv2[ks][j] = q[ks*32 + hi*8 + j]
    float qv2[2][8];
#pragma unroll
    for (int ks = 0; ks < 2; ++ks)
#pragma unroll
        for (int j = 0; j < 8; ++j)
            qv2[ks][j] = q_l[wv * 64 + ks * 32 + hi * 8 + j];

    // A-frags: c * qw'[e = mt*16+lo][dd = ks*32 + hi*8 + j], bf16
    short8 af[4][2];
#pragma unroll
    for (int mt = 0; mt < 4; ++mt) {
        const float* wr = w1 + (mt * 16 + lo) * 192;
#pragma unroll
        for (int ks = 0; ks < 2; ++ks) {
            int dd0 = ks * 32 + hi * 8;
            float4 a0 = *(const float4*)(wr + 128 + dd0);
            float4 a1 = *(const float4*)(wr + 128 + dd0 + 4);
            float4 k0 = *(const float4*)(wr + 64 + dd0);
            float4 k1 = *(const float4*)(wr + 64 + dd0 + 4);
            union { u16 u[8]; short8 s; } cv;
            cv.u[0] = f2b(NA * __builtin_fmaf(qv2[ks][0], a0.x, k0.x));
            cv.u[1] = f2b(NA * __builtin_fmaf(qv2[ks][1], a0.y, k0.y));
            cv.u[2] = f2b(NA * __builtin_fmaf(qv2[ks][2], a0.z, k0.z));
            cv.u[3] = f2b(NA * __builtin_fmaf(qv2[ks][3], a0.w, k0.w));
            cv.u[4] = f2b(NA * __builtin_fmaf(qv2[ks][4], a1.x, k1.x));
            cv.u[5] = f2b(NA * __builtin_fmaf(qv2[ks][5], a1.y, k1.y));
            cv.u[6] = f2b(NA * __builtin_fmaf(qv2[ks][6], a1.z, k1.z));
            cv.u[7] = f2b(NA * __builtin_fmaf(qv2[ks][7], a1.w, k1.w));
            af[mt][ks] = cv.s;
        }
    }

    float l_run = 0.f;
    floatx4 pv[4];
#pragma unroll
    for (int dt = 0; dt < 4; ++dt) pv[dt] = (floatx4){0.f, 0.f, 0.f, 0.f};
    const floatx4 Z = (floatx4){0.f, 0.f, 0.f, 0.f};

    // walking per-lane K pointer (advances 2048 u16/chunk; imm offsets
    // {0,32,1024,1056} u16). Final over-run lands in vthi region, unused.
    const u16* kc = kb + bh * 65536 + lo * 64 + hi * 8;
    // walking V^T pointers, chunk-major layout: +2048 u16/chunk, imm dt*512 u16.
    const u16* vph = vthi + bh * 65536 + lo * 32 + hi * 8;
    const u16* vpl = vtlo + bh * 65536 + lo * 32 + hi * 8;
    u16* psw = p_sw + wv * 32;                     // this wave's staging plane

    // prologue: load B-frags for chunk j=0
    short8 bf[2][2];
    {
        uint4 k00 = *(const uint4*)(kc);
        uint4 k01 = *(const uint4*)(kc + 32);
        uint4 k10 = *(const uint4*)(kc + 1024);
        uint4 k11 = *(const uint4*)(kc + 1056);
        bf[0][0] = *(short8*)&k00; bf[0][1] = *(short8*)&k01;
        bf[1][0] = *(short8*)&k10; bf[1][1] = *(short8*)&k11;
    }

    for (int jc = 0; jc < 32; ++jc) {
        // V hi frags issued at chunk top: full chunk of work hides the latency
        uint4 vh0 = *(const uint4*)(vph);
        uint4 vh1 = *(const uint4*)(vph + 512);
        uint4 vh2 = *(const uint4*)(vph + 1024);
        uint4 vh3 = *(const uint4*)(vph + 1536);

        floatx2 s0v = (floatx2){0.f, 0.f};
        floatx2 s1v = (floatx2){0.f, 0.f};

        // pipeline prologue: mt=0's 4 MFMAs
        floatx4 aP[2], aN[2];
        aP[0] = __builtin_amdgcn_mfma_f32_16x16x32_bf16(af[0][0], bf[0][0], Z, 0, 0, 0);
        aP[0] = __builtin_amdgcn_mfma_f32_16x16x32_bf16(af[0][1], bf[0][1], aP[0], 0, 0, 0);
        aP[1] = __builtin_amdgcn_mfma_f32_16x16x32_bf16(af[0][0], bf[1][0], Z, 0, 0, 0);
        aP[1] = __builtin_amdgcn_mfma_f32_16x16x32_bf16(af[0][1], bf[1][1], aP[1], 0, 0, 0);

#pragma unroll
        for (int mt = 0; mt < 4; ++mt) {
            if (mt < 3) {
                aN[0] = __builtin_amdgcn_mfma_f32_16x16x32_bf16(af[mt + 1][0], bf[0][0], Z, 0, 0, 0);
                aN[0] = __builtin_amdgcn_mfma_f32_16x16x32_bf16(af[mt + 1][1], bf[0][1], aN[0], 0, 0, 0);
                aN[1] = __builtin_amdgcn_mfma_f32_16x16x32_bf16(af[mt + 1][0], bf[1][0], Z, 0, 0, 0);
                aN[1] = __builtin_amdgcn_mfma_f32_16x16x32_bf16(af[mt + 1][1], bf[1][1], aN[1], 0, 0, 0);
            } else {
                // advance + reload K frags for the next chunk
                kc += 2048;
                uint4 k00 = *(const uint4*)(kc);
                uint4 k01 = *(const uint4*)(kc + 32);
                uint4 k10 = *(const uint4*)(kc + 1024);
                uint4 k11 = *(const uint4*)(kc + 1056);
                bf[0][0] = *(short8*)&k00; bf[0][1] = *(short8*)&k01;
                bf[1][0] = *(short8*)&k10; bf[1][1] = *(short8*)&k11;
            }

            // score mt's pair (packed f32): x' = c*hid = aP + qp'
#pragma unroll
            for (int h2 = 0; h2 < 2; ++h2) {
                u32 wp = wcp[mt][h2];
                floatx2 wv2 = (floatx2){u2f(wp << 16), u2f(wp & 0xFFFF0000u)};
                u32 qp = qpp[mt][h2];
                floatx2 qv = (floatx2){u2f(qp << 16), u2f(qp & 0xFFFF0000u)};
#pragma unroll
                for (int t = 0; t < 2; ++t) {
                    floatx2 x = (floatx2){aP[t][h2 * 2 + 0], aP[t][h2 * 2 + 1]} + qv;
                    floatx2 ex = (floatx2){__builtin_amdgcn_exp2f(x.x),
                                           __builtin_amdgcn_exp2f(x.y)};
                    floatx2 a = ex + 1.0f;                       // pk_add
                    float rc = __builtin_amdgcn_rcpf(a.x * a.y);
                    floatx2 sw = (floatx2){a.y, a.x};
                    floatx2 contrib = (x * wv2) * (sw * rc);     // pk_mul x3 -> pk_fma
                    if (t == 0) s0v += contrib; else s1v += contrib;
                }
            }
            aP[0] = aN[0];
            aP[1] = aN[1];
        }

        // V lo frags: issued here, consumed after the tail (~tail latency gap,
        // remainder absorbed by other, desynced waves)
        uint4 vl0 = *(const uint4*)(vpl);
        uint4 vl1 = *(const uint4*)(vpl + 512);
        uint4 vl2 = *(const uint4*)(vpl + 1024);
        uint4 vl3 = *(const uint4*)(vpl + 1536);

        float s0 = s0v.x + s0v.y, s1 = s1v.x + s1v.y;
        s0 += __shfl_xor(s0, 16); s0 += __shfl_xor(s0, 32);   // s[j=lo] (dup over hi)
        s1 += __shfl_xor(s1, 16); s1 += __shfl_xor(s1, 32);   // s[j=16+lo]

        // fixed-shift softmax numerator (scores bounded, safe)
        float p0 = __builtin_amdgcn_exp2f(s0 - 16.0f);
        float p1 = __builtin_amdgcn_exp2f(s1 - 16.0f);
        u16 ph0 = f2b(p0);
        u16 ph1 = f2b(p1);
        l_run += b2f(ph0) + b2f(ph1);              // l from QUANTIZED p

        // stage P in-wave: 32 u16; read back as broadcast A-frag (all rows = P)
        if (lane < 16) {
            psw[lo]      = ph0;                    // p[j=lo]
            psw[16 + lo] = ph1;                    // p[j=16+lo]
        }
        short8 pf = *(const short8*)(psw + hi * 8);   // k=hi*8+i -> p[k], bcast over lo

        // PV: out[d=dt*16+col] += p[k] * V^T frags (hi then lo)
        pv[0] = __builtin_amdgcn_mfma_f32_16x16x32_bf16(pf, *(short8*)&vh0, pv[0], 0, 0, 0);
        pv[1] = __builtin_amdgcn_mfma_f32_16x16x32_bf16(pf, *(short8*)&vh1, pv[1], 0, 0, 0);
        pv[2] = __builtin_amdgcn_mfma_f32_16x16x32_bf16(pf, *(short8*)&vh2, pv[2], 0, 0, 0);
        pv[3] = __builtin_amdgcn_mfma_f32_16x16x32_bf16(pf, *(short8*)&vh3, pv[3], 0, 0, 0);
        pv[0] = __builtin_amdgcn_mfma_f32_16x16x32_bf16(pf, *(short8*)&vl0, pv[0], 0, 0, 0);
        pv[1] = __builtin_amdgcn_mfma_f32_16x16x32_bf16(pf, *(short8*)&vl1, pv[1], 0, 0, 0);
        pv[2] = __builtin_amdgcn_mfma_f32_16x16x32_bf16(pf, *(short8*)&vl2, pv[2], 0, 0, 0);
        pv[3] = __builtin_amdgcn_mfma_f32_16x16x32_bf16(pf, *(short8*)&vl3, pv[3], 0, 0, 0);

        vph += 2048;
        vpl += 2048;
    }

    // per-wave l: sum over the 16 lo lanes (values hi-duplicated)
    float l = l_run;
    l += __shfl_xor(l, 1); l += __shfl_xor(l, 2);
    l += __shfl_xor(l, 4); l += __shfl_xor(l, 8);
    float rl = __builtin_amdgcn_rcpf(l);

    if (hi == 0) {                                 // D row 0 lives at lanes 0..15, reg 0
        int b = bh >> 3, h = bh & 7;
        float* dst = ao + ((size_t)(b * 1024 + qi) * 512) + h * 64 + lo;
        dst[0]  = pv[0][0] * rl;
        dst[16] = pv[1][0] * rl;
        dst[32] = pv[2][0] * rl;
        dst[48] = pv[3][0] * rl;
    }
}

// ---------------------------------------------------------------------------
extern "C" void kernel_launch(void* const* d_in, const int* in_sizes, int n_in,
                              void* d_out, int out_size, void* d_ws, size_t ws_size,
                              hipStream_t stream)
{
    (void)in_sizes; (void)n_in; (void)out_size; (void)ws_size;
    const float* x  = (const float*)d_in[0];
    const float* Wq = (const float*)d_in[1];
    const float* bq = (const float*)d_in[2];
    const float* Wk = (const float*)d_in[3];
    const float* bk = (const float*)d_in[4];
    const float* Wv = (const float*)d_in[5];
    const float* bv = (const float*)d_in[6];
    const float* w1 = (const float*)d_in[7];
    const float* b1 = (const float*)d_in[8];
    const float* w2 = (const float*)d_in[9];
    // d_in[10] = b2: scalar shift of all scores -> softmax-invariant -> unused
    const float* Wo = (const float*)d_in[11];
    const float* bo = (const float*)d_in[12];

    char* ws = (char*)d_ws;
    float* q_ws = (float*)(ws);               // 4 MB fp32 (b,h,c,d)
    u16*   k_ws = (u16*)(ws + (4u << 20));    // 2 MB bf16 (b,h,c,d)
    u16*   vthi = (u16*)(ws + (6u << 20));    // 2 MB bf16 V^T hi, chunk-major
    u16*   vtlo = (u16*)(ws + (8u << 20));    // 2 MB bf16 V^T lo, chunk-major
    float* a_ws = (float*)(ws + (10u << 20)); // 4 MB fp32 (b,c,D)

    dim3 blk(256);
    hipLaunchKernelGGL(gemm_qkv, dim3(32, 24), blk, 0, stream,
                       x, Wq, Wk, Wv, bq, bk, bv, q_ws, k_ws, vthi, vtlo);
    hipLaunchKernelGGL(attn19, dim3(4096), blk, 0, stream,
                       q_ws, k_ws, vthi, vtlo, w1, b1, w2, a_ws);
    hipLaunchKernelGGL(gemm_out, dim3(32, 8), blk, 0, stream, a_ws, Wo, bo, (float*)d_out);
}

// Round 8
// 826.017 us; speedup vs baseline: 1.0476x; 1.0476x over previous
//
#include <hip/hip_runtime.h>
#include <cstdint>

typedef unsigned short u16;
typedef unsigned int u32;
typedef __attribute__((ext_vector_type(8))) short short8;   // 8 bf16 (MFMA A/B frag)
typedef __attribute__((ext_vector_type(4))) float floatx4;  // MFMA C/D frag
typedef __attribute__((ext_vector_type(2))) float floatx2;  // packed f32 pair (v_pk_*_f32)

__device__ __forceinline__ float b2f(u16 u) {
    union { unsigned int i; float f; } c; c.i = ((unsigned int)u) << 16; return c.f;
}
__device__ __forceinline__ u16 f2b(float f) {
    union { float f; unsigned int i; } c; c.f = f;
    unsigned int u = c.i;
    u = u + 0x7FFFu + ((u >> 16) & 1u);   // RNE
    return (u16)(u >> 16);
}
__device__ __forceinline__ float u2f(u32 u) { union { u32 u; float f; } c; c.u = u; return c.f; }

// ---------------------------------------------------------------------------
// Fused Q/K/V projection GEMM. Y[m,n] = sum_k x[m,k]*W[n,k] + bias[n].
// grid (32, 24): which = blockIdx.y>>3 (0=q fp32, 1=k bf16, 2=v).
// For which==2 the 64x64 tile is transposed through LDS and stored CHUNK-MAJOR
// as vt[bh][chunk=c>>5][dt=d>>4][d&15][c&31] (bf16 hi + bf16 lo residual) so
// the attention PV step loads B-frags via one walking pointer + imm offsets.
// ---------------------------------------------------------------------------
__global__ __launch_bounds__(256) void gemm_qkv(
    const float* __restrict__ x,
    const float* __restrict__ Wq, const float* __restrict__ Wk, const float* __restrict__ Wv,
    const float* __restrict__ bq, const float* __restrict__ bk, const float* __restrict__ bv,
    float* __restrict__ qout, u16* __restrict__ kout,
    u16* __restrict__ vthi, u16* __restrict__ vtlo)
{
    __shared__ u16 xs[64 * 72];
    __shared__ u16 wsl[64 * 72];
    int tid = threadIdx.x;
    int lane = tid & 63;
    int wv = tid >> 6;
    int lo = lane & 15, hi = lane >> 4;
    int which = blockIdx.y >> 3;
    int m0 = blockIdx.x * 64, n0 = (blockIdx.y & 7) * 64;
    const float* W    = which == 0 ? Wq : (which == 1 ? Wk : Wv);
    const float* bias = which == 0 ? bq : (which == 1 ? bk : bv);

    floatx4 acc[4];
#pragma unroll
    for (int mt = 0; mt < 4; ++mt) acc[mt] = (floatx4){0.f, 0.f, 0.f, 0.f};

    for (int k0 = 0; k0 < 512; k0 += 64) {
        __syncthreads();
#pragma unroll
        for (int i = 0; i < 2; ++i) {
            int v = tid + i * 256;
            int row = v >> 3, c8 = (v & 7) * 8;
            const float* ap = x + (m0 + row) * 512 + k0 + c8;
            const float* wp = W + (n0 + row) * 512 + k0 + c8;
            float4 a0 = *(const float4*)(ap);
            float4 a1 = *(const float4*)(ap + 4);
            float4 w0 = *(const float4*)(wp);
            float4 w1v = *(const float4*)(wp + 4);
            union { u16 u[8]; uint4 q; } ca, cw;
            ca.u[0] = f2b(a0.x); ca.u[1] = f2b(a0.y); ca.u[2] = f2b(a0.z); ca.u[3] = f2b(a0.w);
            ca.u[4] = f2b(a1.x); ca.u[5] = f2b(a1.y); ca.u[6] = f2b(a1.z); ca.u[7] = f2b(a1.w);
            cw.u[0] = f2b(w0.x); cw.u[1] = f2b(w0.y); cw.u[2] = f2b(w0.z); cw.u[3] = f2b(w0.w);
            cw.u[4] = f2b(w1v.x); cw.u[5] = f2b(w1v.y); cw.u[6] = f2b(w1v.z); cw.u[7] = f2b(w1v.w);
            *(uint4*)(xs + row * 72 + c8)  = ca.q;
            *(uint4*)(wsl + row * 72 + c8) = cw.q;
        }
        __syncthreads();
#pragma unroll
        for (int ks = 0; ks < 2; ++ks) {
            short8 bfr = *(const short8*)(wsl + (wv * 16 + lo) * 72 + ks * 32 + hi * 8);
#pragma unroll
            for (int mt = 0; mt < 4; ++mt) {
                short8 afr = *(const short8*)(xs + (mt * 16 + lo) * 72 + ks * 32 + hi * 8);
                acc[mt] = __builtin_amdgcn_mfma_f32_16x16x32_bf16(afr, bfr, acc[mt], 0, 0, 0);
            }
        }
    }

    int n = n0 + wv * 16 + lo;
    float bv2 = bias[n];
    if (which == 2) {
        // transpose V tile through LDS; emit vt_hi/vt_lo bf16, chunk-major layout
        __syncthreads();                           // xs/wsl reuse: all waves done with MFMAs
        int nl = wv * 16 + lo;                     // local d
#pragma unroll
        for (int mt = 0; mt < 4; ++mt)
#pragma unroll
            for (int r = 0; r < 4; ++r) {
                int ml = mt * 16 + hi * 4 + r;     // local c
                float y = acc[mt][r] + bv2;
                u16 vh = f2b(y);
                u16 vl = f2b(y - b2f(vh));
                xs[nl * 72 + ml]  = vh;
                wsl[nl * 72 + ml] = vl;
            }
        __syncthreads();
        int row = tid >> 2, seg = (tid & 3) * 16;  // row = local d, seg = local c chunk
        int b = m0 >> 10, c0 = m0 & 1023, h2 = n0 >> 6;
        int cc = c0 + seg;                         // global c of this 16-piece (within one 32-chunk)
        size_t dst = (size_t)(b * 8 + h2) * 65536 + (cc >> 5) * 2048
                   + (row >> 4) * 512 + (row & 15) * 32 + (cc & 31);
        *(uint4*)(vthi + dst)     = *(uint4*)(xs  + row * 72 + seg);
        *(uint4*)(vthi + dst + 8) = *(uint4*)(xs  + row * 72 + seg + 8);
        *(uint4*)(vtlo + dst)     = *(uint4*)(wsl + row * 72 + seg);
        *(uint4*)(vtlo + dst + 8) = *(uint4*)(wsl + row * 72 + seg + 8);
    } else {
        int h = n >> 6, dd = n & 63;
#pragma unroll
        for (int mt = 0; mt < 4; ++mt)
#pragma unroll
            for (int r = 0; r < 4; ++r) {
                int m = m0 + mt * 16 + hi * 4 + r;  // C/D: row=(lane>>4)*4+reg, col=lane&15
                float y = acc[mt][r] + bv2;
                int b = m >> 10, c = m & 1023;
                int idx = (((b * 8 + h) * 1024) + c) * 64 + dd;
                if (which == 0) qout[idx] = y;
                else            kout[idx] = f2b(y);
            }
    }
}

// ---------------------------------------------------------------------------
// Output GEMM: Y[m,n] = sum_k A[m,k]*Wo[n,k] + bo[n], fp32 out, [m*512+n].
// ---------------------------------------------------------------------------
__global__ __launch_bounds__(256) void gemm_out(
    const float* __restrict__ A, const float* __restrict__ W, const float* __restrict__ bias,
    float* __restrict__ outf)
{
    __shared__ u16 xs[64 * 72];
    __shared__ u16 wsl[64 * 72];
    int tid = threadIdx.x;
    int lane = tid & 63;
    int wv = tid >> 6;
    int lo = lane & 15, hi = lane >> 4;
    int m0 = blockIdx.x * 64, n0 = blockIdx.y * 64;

    floatx4 acc[4];
#pragma unroll
    for (int mt = 0; mt < 4; ++mt) acc[mt] = (floatx4){0.f, 0.f, 0.f, 0.f};

    for (int k0 = 0; k0 < 512; k0 += 64) {
        __syncthreads();
#pragma unroll
        for (int i = 0; i < 2; ++i) {
            int v = tid + i * 256;
            int row = v >> 3, c8 = (v & 7) * 8;
            const float* ap = A + (m0 + row) * 512 + k0 + c8;
            const float* wp = W + (n0 + row) * 512 + k0 + c8;
            float4 a0 = *(const float4*)(ap);
            float4 a1 = *(const float4*)(ap + 4);
            float4 w0 = *(const float4*)(wp);
            float4 w1v = *(const float4*)(wp + 4);
            union { u16 u[8]; uint4 q; } ca, cw;
            ca.u[0] = f2b(a0.x); ca.u[1] = f2b(a0.y); ca.u[2] = f2b(a0.z); ca.u[3] = f2b(a0.w);
            ca.u[4] = f2b(a1.x); ca.u[5] = f2b(a1.y); ca.u[6] = f2b(a1.z); ca.u[7] = f2b(a1.w);
            cw.u[0] = f2b(w0.x); cw.u[1] = f2b(w0.y); cw.u[2] = f2b(w0.z); cw.u[3] = f2b(w0.w);
            cw.u[4] = f2b(w1v.x); cw.u[5] = f2b(w1v.y); cw.u[6] = f2b(w1v.z); cw.u[7] = f2b(w1v.w);
            *(uint4*)(xs + row * 72 + c8)  = ca.q;
            *(uint4*)(wsl + row * 72 + c8) = cw.q;
        }
        __syncthreads();
#pragma unroll
        for (int ks = 0; ks < 2; ++ks) {
            short8 bfr = *(const short8*)(wsl + (wv * 16 + lo) * 72 + ks * 32 + hi * 8);
#pragma unroll
            for (int mt = 0; mt < 4; ++mt) {
                short8 afr = *(const short8*)(xs + (mt * 16 + lo) * 72 + ks * 32 + hi * 8);
                acc[mt] = __builtin_amdgcn_mfma_f32_16x16x32_bf16(afr, bfr, acc[mt], 0, 0, 0);
            }
        }
    }

    int n = n0 + wv * 16 + lo;
    float bv = bias[n];
#pragma unroll
    for (int mt = 0; mt < 4; ++mt)
#pragma unroll
        for (int r = 0; r < 4; ++r) {
            int m = m0 + mt * 16 + hi * 4 + r;
            outf[m * 512 + n] = acc[mt][r] + bv;
        }
}

// ---------------------------------------------------------------------------
// Fused second-order attention, v20 = v19 (independent waves, zero barriers,
// chunk-major V^T, qp' folded into scoring) with the REGISTER SPILLS removed
// (v19 post-mortem: WRITE_SIZE 22->84 MB scratch, VALUBusy 29% -- staging
// vh+vl = 32 regs blew the 128-reg tier):
//  (1) PV split into two sequential phases: vh0..3 staged at chunk top
//      (latency hidden under scoring), PV-hi x4 MFMAs, then vl0..3 loaded
//      into the now-dead vh registers, PV-lo x4. Peak V staging 16 regs.
//      The vl-load stall is per-wave and absorbed by the 3 other drifting
//      waves on the SIMD (no barriers anywhere).
//  (2) vpl walking pointer dropped: vtlo = vthi + 2MB layout constant, so
//      vpl = vph + (1<<20) elements, recomputed per chunk (2 VALU, -2 regs).
// Math identical to v19 (passed, absmax 7.3e-4).
// ---------------------------------------------------------------------------
__global__ __launch_bounds__(256, 4) void attn20(
    const float* __restrict__ qf, const u16* __restrict__ kb,
    const u16* __restrict__ vthi, const u16* __restrict__ vtlo,
    const float* __restrict__ w1, const float* __restrict__ b1, const float* __restrict__ w2,
    float* __restrict__ ao)
{
    __shared__ float q_l[4 * 64];
    __shared__ __align__(16) u16 p_sw[4 * 32];     // per-wave P staging (64 B each)
    int tid = threadIdx.x;
    int lane = tid & 63;
    int wv = tid >> 6;
    int lo = lane & 15, hi = lane >> 4;
    int bh = blockIdx.x >> 8;                      // 0..15 = b*8+h
    int qbase = (blockIdx.x & 255) << 2;           // block's first query
    int qi = qbase | wv;                           // this wave's query

    const float NA = -2.45546696f;                 // -1.702 * log2(e)

    q_l[wv * 64 + lane] = qf[(bh * 1024 + qi) * 64 + lane];   // wave-private segment

    // qp[e]+b1[e] at lane=e
    float qpacc = b1[lane];
#pragma unroll
    for (int d8 = 0; d8 < 64; d8 += 8) {
        float4 wa = *(const float4*)(w1 + lane * 192 + d8);
        float4 wb = *(const float4*)(w1 + lane * 192 + d8 + 4);
        const float* q8 = q_l + wv * 64 + d8;      // wave-uniform broadcast reads
        qpacc = __builtin_fmaf(q8[0], wa.x, qpacc);
        qpacc = __builtin_fmaf(q8[1], wa.y, qpacc);
        qpacc = __builtin_fmaf(q8[2], wa.z, qpacc);
        qpacc = __builtin_fmaf(q8[3], wa.w, qpacc);
        qpacc = __builtin_fmaf(q8[4], wb.x, qpacc);
        qpacc = __builtin_fmaf(q8[5], wb.y, qpacc);
        qpacc = __builtin_fmaf(q8[6], wb.z, qpacc);
        qpacc = __builtin_fmaf(q8[7], wb.w, qpacc);
    }
    qpacc *= NA;                                   // qp' = c * (qp + b1)

    // w2c packed: wc' = w2[e] * (1/8)*log2e / c ; qp' packed the same way
    u32 wcp[4][2];
    u32 qpp[4][2];
    float w2row = w2[lane] * -0.07344288f;
#pragma unroll
    for (int mt = 0; mt < 4; ++mt)
#pragma unroll
        for (int h2 = 0; h2 < 2; ++h2) {
            int e0 = mt * 16 + hi * 4 + h2 * 2;
            u32 wlo = (u32)f2b(__shfl(w2row, e0));
            u32 whi = (u32)f2b(__shfl(w2row, e0 + 1));
            wcp[mt][h2] = (whi << 16) | wlo;
            u32 qlo = (u32)f2b(__shfl(qpacc, e0));
            u32 qhi = (u32)f2b(__shfl(qpacc, e0 + 1));
            qpp[mt][h2] = (qhi << 16) | qlo;
        }

    // q pieces for frag build: qv2[ks][j] = q[ks*32 + hi*8 + j]
    float qv2[2][8];
#pragma unroll
    for (int ks = 0; ks < 2; ++ks)
#pragma unroll
        for (int j = 0; j < 8; ++j)
            qv2[ks][j] = q_l[wv * 64 + ks * 32 + hi * 8 + j];

    // A-frags: c * qw'[e = mt*16+lo][dd = ks*32 + hi*8 + j], bf16
    short8 af[4][2];
#pragma unroll
    for (int mt = 0; mt < 4; ++mt) {
        const float* wr = w1 + (mt * 16 + lo) * 192;
#pragma unroll
        for (int ks = 0; ks < 2; ++ks) {
            int dd0 = ks * 32 + hi * 8;
            float4 a0 = *(const float4*)(wr + 128 + dd0);
            float4 a1 = *(const float4*)(wr + 128 + dd0 + 4);
            float4 k0 = *(const float4*)(wr + 64 + dd0);
            float4 k1 = *(const float4*)(wr + 64 + dd0 + 4);
            union { u16 u[8]; short8 s; } cv;
            cv.u[0] = f2b(NA * __builtin_fmaf(qv2[ks][0], a0.x, k0.x));
            cv.u[1] = f2b(NA * __builtin_fmaf(qv2[ks][1], a0.y, k0.y));
            cv.u[2] = f2b(NA * __builtin_fmaf(qv2[ks][2], a0.z, k0.z));
            cv.u[3] = f2b(NA * __builtin_fmaf(qv2[ks][3], a0.w, k0.w));
            cv.u[4] = f2b(NA * __builtin_fmaf(qv2[ks][4], a1.x, k1.x));
            cv.u[5] = f2b(NA * __builtin_fmaf(qv2[ks][5], a1.y, k1.y));
            cv.u[6] = f2b(NA * __builtin_fmaf(qv2[ks][6], a1.z, k1.z));
            cv.u[7] = f2b(NA * __builtin_fmaf(qv2[ks][7], a1.w, k1.w));
            af[mt][ks] = cv.s;
        }
    }

    float l_run = 0.f;
    floatx4 pv[4];
#pragma unroll
    for (int dt = 0; dt < 4; ++dt) pv[dt] = (floatx4){0.f, 0.f, 0.f, 0.f};
    const floatx4 Z = (floatx4){0.f, 0.f, 0.f, 0.f};

    // walking per-lane K pointer (advances 2048 u16/chunk; imm offsets
    // {0,32,1024,1056} u16). Final over-run lands in vthi region, unused.
    const u16* kc = kb + bh * 65536 + lo * 64 + hi * 8;
    // walking V^T hi pointer, chunk-major layout: +2048 u16/chunk, imm dt*512.
    // lo pointer derived per chunk: vtlo = vthi + (1<<20) u16 (layout const).
    const u16* vph = vthi + bh * 65536 + lo * 32 + hi * 8;
    u16* psw = p_sw + wv * 32;                     // this wave's staging plane

    // prologue: load B-frags for chunk j=0
    short8 bf[2][2];
    {
        uint4 k00 = *(const uint4*)(kc);
        uint4 k01 = *(const uint4*)(kc + 32);
        uint4 k10 = *(const uint4*)(kc + 1024);
        uint4 k11 = *(const uint4*)(kc + 1056);
        bf[0][0] = *(short8*)&k00; bf[0][1] = *(short8*)&k01;
        bf[1][0] = *(short8*)&k10; bf[1][1] = *(short8*)&k11;
    }

    for (int jc = 0; jc < 32; ++jc) {
        // V hi frags issued at chunk top: full chunk of scoring hides latency
        uint4 vh0 = *(const uint4*)(vph);
        uint4 vh1 = *(const uint4*)(vph + 512);
        uint4 vh2 = *(const uint4*)(vph + 1024);
        uint4 vh3 = *(const uint4*)(vph + 1536);

        floatx2 s0v = (floatx2){0.f, 0.f};
        floatx2 s1v = (floatx2){0.f, 0.f};

        // pipeline prologue: mt=0's 4 MFMAs
        floatx4 aP[2], aN[2];
        aP[0] = __builtin_amdgcn_mfma_f32_16x16x32_bf16(af[0][0], bf[0][0], Z, 0, 0, 0);
        aP[0] = __builtin_amdgcn_mfma_f32_16x16x32_bf16(af[0][1], bf[0][1], aP[0], 0, 0, 0);
        aP[1] = __builtin_amdgcn_mfma_f32_16x16x32_bf16(af[0][0], bf[1][0], Z, 0, 0, 0);
        aP[1] = __builtin_amdgcn_mfma_f32_16x16x32_bf16(af[0][1], bf[1][1], aP[1], 0, 0, 0);

#pragma unroll
        for (int mt = 0; mt < 4; ++mt) {
            if (mt < 3) {
                aN[0] = __builtin_amdgcn_mfma_f32_16x16x32_bf16(af[mt + 1][0], bf[0][0], Z, 0, 0, 0);
                aN[0] = __builtin_amdgcn_mfma_f32_16x16x32_bf16(af[mt + 1][1], bf[0][1], aN[0], 0, 0, 0);
                aN[1] = __builtin_amdgcn_mfma_f32_16x16x32_bf16(af[mt + 1][0], bf[1][0], Z, 0, 0, 0);
                aN[1] = __builtin_amdgcn_mfma_f32_16x16x32_bf16(af[mt + 1][1], bf[1][1], aN[1], 0, 0, 0);
            } else {
                // advance + reload K frags for the next chunk
                kc += 2048;
                uint4 k00 = *(const uint4*)(kc);
                uint4 k01 = *(const uint4*)(kc + 32);
                uint4 k10 = *(const uint4*)(kc + 1024);
                uint4 k11 = *(const uint4*)(kc + 1056);
                bf[0][0] = *(short8*)&k00; bf[0][1] = *(short8*)&k01;
                bf[1][0] = *(short8*)&k10; bf[1][1] = *(short8*)&k11;
            }

            // score mt's pair (packed f32): x' = c*hid = aP + qp'
#pragma unroll
            for (int h2 = 0; h2 < 2; ++h2) {
                u32 wp = wcp[mt][h2];
                floatx2 wv2 = (floatx2){u2f(wp << 16), u2f(wp & 0xFFFF0000u)};
                u32 qp = qpp[mt][h2];
                floatx2 qv = (floatx2){u2f(qp << 16), u2f(qp & 0xFFFF0000u)};
#pragma unroll
                for (int t = 0; t < 2; ++t) {
                    floatx2 x = (floatx2){aP[t][h2 * 2 + 0], aP[t][h2 * 2 + 1]} + qv;
                    floatx2 ex = (floatx2){__builtin_amdgcn_exp2f(x.x),
                                           __builtin_amdgcn_exp2f(x.y)};
                    floatx2 a = ex + 1.0f;                       // pk_add
                    float rc = __builtin_amdgcn_rcpf(a.x * a.y);
                    floatx2 sw = (floatx2){a.y, a.x};
                    floatx2 contrib = (x * wv2) * (sw * rc);     // pk_mul x3 -> pk_fma
                    if (t == 0) s0v += contrib; else s1v += contrib;
                }
            }
            aP[0] = aN[0];
            aP[1] = aN[1];
        }

        float s0 = s0v.x + s0v.y, s1 = s1v.x + s1v.y;
        s0 += __shfl_xor(s0, 16); s0 += __shfl_xor(s0, 32);   // s[j=lo] (dup over hi)
        s1 += __shfl_xor(s1, 16); s1 += __shfl_xor(s1, 32);   // s[j=16+lo]

        // fixed-shift softmax numerator (scores bounded, safe)
        float p0 = __builtin_amdgcn_exp2f(s0 - 16.0f);
        float p1 = __builtin_amdgcn_exp2f(s1 - 16.0f);
        u16 ph0 = f2b(p0);
        u16 ph1 = f2b(p1);
        l_run += b2f(ph0) + b2f(ph1);              // l from QUANTIZED p

        // stage P in-wave: 32 u16; read back as broadcast A-frag (all rows = P)
        if (lane < 16) {
            psw[lo]      = ph0;                    // p[j=lo]
            psw[16 + lo] = ph1;                    // p[j=16+lo]
        }
        short8 pf = *(const short8*)(psw + hi * 8);   // k=hi*8+i -> p[k], bcast over lo

        // PV phase 1 (hi): out[d=dt*16+col] += p[k] * V^T_hi
        pv[0] = __builtin_amdgcn_mfma_f32_16x16x32_bf16(pf, *(short8*)&vh0, pv[0], 0, 0, 0);
        pv[1] = __builtin_amdgcn_mfma_f32_16x16x32_bf16(pf, *(short8*)&vh1, pv[1], 0, 0, 0);
        pv[2] = __builtin_amdgcn_mfma_f32_16x16x32_bf16(pf, *(short8*)&vh2, pv[2], 0, 0, 0);
        pv[3] = __builtin_amdgcn_mfma_f32_16x16x32_bf16(pf, *(short8*)&vh3, pv[3], 0, 0, 0);

        // PV phase 2 (lo): loads reuse the dead vh registers; the vmcnt stall
        // here is per-wave and absorbed by the other drifting waves.
        const u16* vpl = vph + (1u << 20);         // vtlo = vthi + 2MB
        uint4 vl0 = *(const uint4*)(vpl);
        uint4 vl1 = *(const uint4*)(vpl + 512);
        uint4 vl2 = *(const uint4*)(vpl + 1024);
        uint4 vl3 = *(const uint4*)(vpl + 1536);
        pv[0] = __builtin_amdgcn_mfma_f32_16x16x32_bf16(pf, *(short8*)&vl0, pv[0], 0, 0, 0);
        pv[1] = __builtin_amdgcn_mfma_f32_16x16x32_bf16(pf, *(short8*)&vl1, pv[1], 0, 0, 0);
        pv[2] = __builtin_amdgcn_mfma_f32_16x16x32_bf16(pf, *(short8*)&vl2, pv[2], 0, 0, 0);
        pv[3] = __builtin_amdgcn_mfma_f32_16x16x32_bf16(pf, *(short8*)&vl3, pv[3], 0, 0, 0);

        vph += 2048;
    }

    // per-wave l: sum over the 16 lo lanes (values hi-duplicated)
    float l = l_run;
    l += __shfl_xor(l, 1); l += __shfl_xor(l, 2);
    l += __shfl_xor(l, 4); l += __shfl_xor(l, 8);
    float rl = __builtin_amdgcn_rcpf(l);

    if (hi == 0) {                                 // D row 0 lives at lanes 0..15, reg 0
        int b = bh >> 3, h = bh & 7;
        float* dst = ao + ((size_t)(b * 1024 + qi) * 512) + h * 64 + lo;
        dst[0]  = pv[0][0] * rl;
        dst[16] = pv[1][0] * rl;
        dst[32] = pv[2][0] * rl;
        dst[48] = pv[3][0] * rl;
    }
}

// ---------------------------------------------------------------------------
extern "C" void kernel_launch(void* const* d_in, const int* in_sizes, int n_in,
                              void* d_out, int out_size, void* d_ws, size_t ws_size,
                              hipStream_t stream)
{
    (void)in_sizes; (void)n_in; (void)out_size; (void)ws_size;
    const float* x  = (const float*)d_in[0];
    const float* Wq = (const float*)d_in[1];
    const float* bq = (const float*)d_in[2];
    const float* Wk = (const float*)d_in[3];
    const float* bk = (const float*)d_in[4];
    const float* Wv = (const float*)d_in[5];
    const float* bv = (const float*)d_in[6];
    const float* w1 = (const float*)d_in[7];
    const float* b1 = (const float*)d_in[8];
    const float* w2 = (const float*)d_in[9];
    // d_in[10] = b2: scalar shift of all scores -> softmax-invariant -> unused
    const float* Wo = (const float*)d_in[11];
    const float* bo = (const float*)d_in[12];

    char* ws = (char*)d_ws;
    float* q_ws = (float*)(ws);               // 4 MB fp32 (b,h,c,d)
    u16*   k_ws = (u16*)(ws + (4u << 20));    // 2 MB bf16 (b,h,c,d)
    u16*   vthi = (u16*)(ws + (6u << 20));    // 2 MB bf16 V^T hi, chunk-major
    u16*   vtlo = (u16*)(ws + (8u << 20));    // 2 MB bf16 V^T lo, chunk-major (MUST stay vthi+2MB)
    float* a_ws = (float*)(ws + (10u << 20)); // 4 MB fp32 (b,c,D)

    dim3 blk(256);
    hipLaunchKernelGGL(gemm_qkv, dim3(32, 24), blk, 0, stream,
                       x, Wq, Wk, Wv, bq, bk, bv, q_ws, k_ws, vthi, vtlo);
    hipLaunchKernelGGL(attn20, dim3(4096), blk, 0, stream,
                       q_ws, k_ws, vthi, vtlo, w1, b1, w2, a_ws);
    hipLaunchKernelGGL(gemm_out, dim3(32, 8), blk, 0, stream, a_ws, Wo, bo, (float*)d_out);
}